// Round 4
// baseline (261.182 us; speedup 1.0000x reference)
//
#include <hip/hip_runtime.h>
#include <hip/hip_bf16.h>

// nnvit_82042465288319 on MI355X (gfx950). B=262144 rows; y[5][32]; 2 layers
// (H=8, HD=4); out = y[0] after layer 1. f32 in/out per reference (runtime
// dtype probe keeps a bf16 path).
//
// Round 4: pi-permuted K axis, zero cross-lane traffic.
//  - wave = 16 batch rows; lane = (quad=lane>>4, nl=lane&15).
//  - All GEMMs mfma_f32_16x16x32_f16, A = weight (m=out-ch), B = y^T (n=batch).
//  - K-axis permutation pi(q*8+j) = j<4 ? 4q+j : 16+4q+(j-4), applied to the
//    WEIGHTS at prep time for qkv AND proj. Then the per-lane channel groups of
//    {y B-operand} == {qkv C output} == {attention o} == {proj B operand} ==
//    {proj C output} == {residual target}: the whole layer chain is per-lane.
//    No __shfl, no LDS, no bank conflicts (round-3: 3.4M conflict cycles).
//  - Attention fully per-lane: lane (q,nl) owns heads {q, q+4} of batch nl.
//  - Layer 1: q/attention/proj only for token 0 (output needs only y[0]).

#define NTOK 5

typedef decltype(__builtin_amdgcn_cvt_pkrtz(0.0f, 0.0f)) half2_t;
using half8_t = __attribute__((ext_vector_type(8))) _Float16;
using f32x4 = __attribute__((ext_vector_type(4))) float;

union H2 { half2_t h; unsigned int u; };
union H8 { half8_t h; uint4 u4; unsigned int u[4]; };

__device__ __forceinline__ half2_t u2h(unsigned int x) { H2 c; c.u = x; return c.h; }
__device__ __forceinline__ unsigned int h2u(half2_t h) { H2 c; c.h = h; return c.u; }
__device__ __forceinline__ unsigned int pk(float a, float b) {
  return h2u(__builtin_amdgcn_cvt_pkrtz(a, b));
}
__device__ __forceinline__ float bf2f(unsigned short u) {
  union { unsigned int u; float f; } c; c.u = ((unsigned int)u) << 16; return c.f;
}
__device__ __forceinline__ half2_t bfpair2h2(unsigned int u) {
  union { unsigned int u; float f; } lo, hi;
  lo.u = u << 16;
  hi.u = u & 0xffff0000u;
  return __builtin_amdgcn_cvt_pkrtz(lo.f, hi.f);  // exact here
}
__device__ __forceinline__ unsigned int f2bfpair(float a, float b) {  // RNE pack
  unsigned int ua = __float_as_uint(a), ub = __float_as_uint(b);
  ua = (ua + 0x7fffu + ((ua >> 16) & 1u)) >> 16;
  ub = (ub + 0x7fffu + ((ub >> 16) & 1u)) & 0xffff0000u;
  return ua | ub;
}

// dtype probe: low 16 bits form a normal-band bf16 exponent iff data is bf16
__device__ __forceinline__ int detect_bf16(const unsigned int* __restrict__ p) {
  int cnt = 0;
#pragma unroll
  for (int i = 0; i < 64; ++i) {
    unsigned int e = (p[i] >> 7) & 0xffu;
    cnt += (e >= 96u && e <= 150u) ? 1 : 0;
  }
  return (cnt >= 40) ? 1 : 0;
}

// ---------------- prep: weights -> fp16 in pi-permuted A layout ----------------
// ws: wqkv u32[3072]@0 | wproj u32[1024]@12288 | bqkv f32[192]@16384
//     bproj f32[64]@17152 | pb f32[400]@17408 | flag int@19008
// A-layout dword i: R=i>>4 (global out-row), q=(i>>2)&3, d=i&3;
//   source channel base = d<2 ? 4q+2d : 16+4q+2(d-2); pack (base, base+1).
__global__ void prep_kernel(const void* __restrict__ xraw,
                            const void* __restrict__ qkv_w, const void* __restrict__ qkv_b,
                            const void* __restrict__ proj_w, const void* __restrict__ proj_b,
                            const void* __restrict__ pos_b,
                            unsigned int* __restrict__ wqkv, unsigned int* __restrict__ wproj,
                            float* __restrict__ bqkv, float* __restrict__ bproj,
                            float* __restrict__ pb, int* __restrict__ flag) {
  const int t = threadIdx.x + blockIdx.x * blockDim.x;
  const int stride = blockDim.x * gridDim.x;
  const int isbf = detect_bf16((const unsigned int*)xraw);  // same answer in every thread
  if (t == 0) *flag = isbf;
#define PI_SRC(i, R, c0)                                    \
  const int R = (i) >> 4;                                   \
  const int q_ = ((i) >> 2) & 3, d_ = (i) & 3;              \
  const int c0 = (d_ < 2) ? (4 * q_ + 2 * d_) : (16 + 4 * q_ + 2 * (d_ - 2));
  if (isbf) {
    const unsigned short* qw = (const unsigned short*)qkv_w;
    const unsigned short* qb = (const unsigned short*)qkv_b;
    const unsigned short* pw = (const unsigned short*)proj_w;
    const unsigned short* pbb = (const unsigned short*)proj_b;
    const unsigned short* pp = (const unsigned short*)pos_b;
    for (int i = t; i < 3072; i += stride) {
      PI_SRC(i, R, c0)
      wqkv[i] = h2u(__builtin_amdgcn_cvt_pkrtz(bf2f(qw[R * 32 + c0]), bf2f(qw[R * 32 + c0 + 1])));
    }
    for (int i = t; i < 1024; i += stride) {
      PI_SRC(i, R, c0)
      wproj[i] = h2u(__builtin_amdgcn_cvt_pkrtz(bf2f(pw[R * 32 + c0]), bf2f(pw[R * 32 + c0 + 1])));
    }
    for (int i = t; i < 192; i += stride) bqkv[i] = bf2f(qb[i]);
    for (int i = t; i < 64; i += stride) bproj[i] = bf2f(pbb[i]);
    for (int i = t; i < 400; i += stride) pb[i] = bf2f(pp[i]);
  } else {
    const float* qw = (const float*)qkv_w;
    const float* qb = (const float*)qkv_b;
    const float* pw = (const float*)proj_w;
    const float* pbb = (const float*)proj_b;
    const float* pp = (const float*)pos_b;
    for (int i = t; i < 3072; i += stride) {
      PI_SRC(i, R, c0)
      wqkv[i] = h2u(__builtin_amdgcn_cvt_pkrtz(qw[R * 32 + c0], qw[R * 32 + c0 + 1]));
    }
    for (int i = t; i < 1024; i += stride) {
      PI_SRC(i, R, c0)
      wproj[i] = h2u(__builtin_amdgcn_cvt_pkrtz(pw[R * 32 + c0], pw[R * 32 + c0 + 1]));
    }
    for (int i = t; i < 192; i += stride) bqkv[i] = qb[i];
    for (int i = t; i < 64; i += stride) bproj[i] = pbb[i];
    for (int i = t; i < 400; i += stride) pb[i] = pp[i];
  }
#undef PI_SRC
}

__device__ __forceinline__ half8_t ldfrag(const uint4* __restrict__ w, int row, int quad) {
  H8 c; c.u4 = w[row * 4 + quad]; return c.h;
}
__device__ __forceinline__ half8_t mk8(const unsigned int (&d)[4]) {
  H8 c; c.u[0] = d[0]; c.u[1] = d[1]; c.u[2] = d[2]; c.u[3] = d[3]; return c.h;
}

// qkv for one token: tiles [TMIN,6): 0/1=q heads {q,q+4}, 2/3=k, 4/5=v
template <int TMIN>
__device__ __forceinline__ void qkv_token(const half8_t (&wa)[6], const f32x4 (&bias)[6],
                                          half8_t yb, unsigned int (&outdw)[6][2]) {
#pragma unroll
  for (int tile = TMIN; tile < 6; ++tile) {
    f32x4 acc = __builtin_amdgcn_mfma_f32_16x16x32_f16(wa[tile], yb, bias[tile], 0, 0, 0);
    outdw[tile][0] = pk(acc[0], acc[1]);
    outdw[tile][1] = pk(acc[2], acc[3]);
  }
}

// per-lane attention, NR q-rows; slot s -> head quad+4s
template <int NR>
__device__ __forceinline__ void attention(const unsigned int (&dw)[NTOK][6][2],
                                          const float* __restrict__ pbl, int quad,
                                          unsigned int (&od)[NR][4]) {
#pragma unroll
  for (int s = 0; s < 2; ++s) {
    const float* pbh = pbl + (quad + 4 * s) * 25;
    float vf[NTOK][4];
#pragma unroll
    for (int m = 0; m < NTOK; ++m) {
      half2_t v0 = u2h(dw[m][4 + s][0]), v1 = u2h(dw[m][4 + s][1]);
      vf[m][0] = (float)v0.x; vf[m][1] = (float)v0.y;
      vf[m][2] = (float)v1.x; vf[m][3] = (float)v1.y;
    }
#pragma unroll
    for (int n = 0; n < NR; ++n) {
      float lg[NTOK];
#pragma unroll
      for (int m = 0; m < NTOK; ++m) {
        float d = __builtin_amdgcn_fdot2(u2h(dw[n][0 + s][0]), u2h(dw[m][2 + s][0]), 0.0f, false);
        d = __builtin_amdgcn_fdot2(u2h(dw[n][0 + s][1]), u2h(dw[m][2 + s][1]), d, false);
        lg[m] = fmaf(d, 0.5f, pbh[n * 5 + m]);  // scale = HD^-0.5 = 0.5
      }
      float mx = fmaxf(fmaxf(fmaxf(lg[0], lg[1]), fmaxf(lg[2], lg[3])), lg[4]);
      float e[NTOK], ssum = 0.0f;
#pragma unroll
      for (int m = 0; m < NTOK; ++m) {
        e[m] = __builtin_amdgcn_exp2f((lg[m] - mx) * 1.44269504f);
        ssum += e[m];
      }
      const float r = __builtin_amdgcn_rcpf(ssum);
      float o0 = 0.f, o1 = 0.f, o2 = 0.f, o3 = 0.f;
#pragma unroll
      for (int m = 0; m < NTOK; ++m) {
        o0 = fmaf(e[m], vf[m][0], o0); o1 = fmaf(e[m], vf[m][1], o1);
        o2 = fmaf(e[m], vf[m][2], o2); o3 = fmaf(e[m], vf[m][3], o3);
      }
      // slot s writes dwords 2s, 2s+1: exactly the pi-layout proj-B operand
      od[n][2 * s + 0] = pk(o0 * r, o1 * r);
      od[n][2 * s + 1] = pk(o2 * r, o3 * r);
    }
  }
}

// ---------------- main kernel: 1 wave = 16 batch rows, zero LDS ----------------
__global__ __launch_bounds__(256, 4) void vit_kernel(
    const void* __restrict__ x, const void* __restrict__ token,
    const unsigned int* __restrict__ wqkv, const unsigned int* __restrict__ wproj,
    const float* __restrict__ bqkv, const float* __restrict__ bproj,
    const float* __restrict__ pb, const int* __restrict__ flag,
    void* __restrict__ out) {
  const int tid = threadIdx.x;
  const int wave = tid >> 6, lane = tid & 63;
  const int quad = lane >> 4, nl = lane & 15;
  const size_t b = (size_t)blockIdx.x * 64 + wave * 16 + nl;
  const int isbf = *flag;  // wave-uniform

  // y in pi B-layout: yd[t] dwords = ch pairs (4q,4q+1),(4q+2,4q+3),(16+4q,..),(16+4q+2,..)
  unsigned int yd[NTOK][4];
  if (isbf) {
    const unsigned short* tk = (const unsigned short*)token;
    uint2 a0 = *(const uint2*)(tk + 4 * quad), a1 = *(const uint2*)(tk + 16 + 4 * quad);
    yd[0][0] = h2u(bfpair2h2(a0.x)); yd[0][1] = h2u(bfpair2h2(a0.y));
    yd[0][2] = h2u(bfpair2h2(a1.x)); yd[0][3] = h2u(bfpair2h2(a1.y));
#pragma unroll
    for (int t = 1; t < NTOK; ++t) {
      const unsigned short* xp = (const unsigned short*)x + b * 128 + (t - 1) * 32;
      uint2 u0 = *(const uint2*)(xp + 4 * quad), u1 = *(const uint2*)(xp + 16 + 4 * quad);
      yd[t][0] = h2u(bfpair2h2(u0.x)); yd[t][1] = h2u(bfpair2h2(u0.y));
      yd[t][2] = h2u(bfpair2h2(u1.x)); yd[t][3] = h2u(bfpair2h2(u1.y));
    }
  } else {
    const float* tk = (const float*)token;
    float4 a0 = *(const float4*)(tk + 4 * quad), a1 = *(const float4*)(tk + 16 + 4 * quad);
    yd[0][0] = pk(a0.x, a0.y); yd[0][1] = pk(a0.z, a0.w);
    yd[0][2] = pk(a1.x, a1.y); yd[0][3] = pk(a1.z, a1.w);
#pragma unroll
    for (int t = 1; t < NTOK; ++t) {
      const float* xp = (const float*)x + b * 128 + (t - 1) * 32;
      float4 u0 = *(const float4*)(xp + 4 * quad), u1 = *(const float4*)(xp + 16 + 4 * quad);
      yd[t][0] = pk(u0.x, u0.y); yd[t][1] = pk(u0.z, u0.w);
      yd[t][2] = pk(u1.x, u1.y); yd[t][3] = pk(u1.z, u1.w);
    }
  }

  const uint4* wq4 = (const uint4*)wqkv;
  const uint4* wp4 = (const uint4*)wproj;

  // ===================== layer 0 (full) =====================
  {
    half8_t wa[6]; f32x4 bias[6];
#pragma unroll
    for (int tile = 0; tile < 6; ++tile) {
      wa[tile] = ldfrag(wq4, tile * 16 + nl, quad);
      bias[tile] = *(const f32x4*)(bqkv + tile * 16 + quad * 4);
    }
    unsigned int dw[NTOK][6][2];
#pragma unroll
    for (int t = 0; t < NTOK; ++t) qkv_token<0>(wa, bias, mk8(yd[t]), dw[t]);

    unsigned int od[NTOK][4];
    attention<NTOK>(dw, pb, quad, od);

    half8_t wp[2]; f32x4 bp[2];
#pragma unroll
    for (int tile = 0; tile < 2; ++tile) {
      wp[tile] = ldfrag(wp4, tile * 16 + nl, quad);
      bp[tile] = *(const f32x4*)(bproj + tile * 16 + quad * 4);
    }
#pragma unroll
    for (int t = 0; t < NTOK; ++t) {
      f32x4 p0 = __builtin_amdgcn_mfma_f32_16x16x32_f16(wp[0], mk8(od[t]), bp[0], 0, 0, 0);
      f32x4 p1 = __builtin_amdgcn_mfma_f32_16x16x32_f16(wp[1], mk8(od[t]), bp[1], 0, 0, 0);
      // proj C is already in pi layout: per-lane residual add (v_pk_add_f16)
      yd[t][0] = h2u(u2h(yd[t][0]) + u2h(pk(p0[0], p0[1])));
      yd[t][1] = h2u(u2h(yd[t][1]) + u2h(pk(p0[2], p0[3])));
      yd[t][2] = h2u(u2h(yd[t][2]) + u2h(pk(p1[0], p1[1])));
      yd[t][3] = h2u(u2h(yd[t][3]) + u2h(pk(p1[2], p1[3])));
    }
  }

  // ===================== layer 1 (token-0 output only) =====================
  {
    half8_t wa[6]; f32x4 bias[6];
#pragma unroll
    for (int tile = 0; tile < 6; ++tile) {
      wa[tile] = ldfrag(wq4, 96 + tile * 16 + nl, quad);
      bias[tile] = *(const f32x4*)(bqkv + 96 + tile * 16 + quad * 4);
    }
    unsigned int dw[NTOK][6][2];
    qkv_token<0>(wa, bias, mk8(yd[0]), dw[0]);  // token 0: q,k,v
#pragma unroll
    for (int t = 1; t < NTOK; ++t) qkv_token<2>(wa, bias, mk8(yd[t]), dw[t]);  // k,v only

    unsigned int od[1][4];
    attention<1>(dw, pb + 200, quad, od);

    half8_t wp[2]; f32x4 bp[2];
#pragma unroll
    for (int tile = 0; tile < 2; ++tile) {
      wp[tile] = ldfrag(wp4, 32 + tile * 16 + nl, quad);
      bp[tile] = *(const f32x4*)(bproj + 32 + tile * 16 + quad * 4);
    }
    f32x4 p0 = __builtin_amdgcn_mfma_f32_16x16x32_f16(wp[0], mk8(od[0]), bp[0], 0, 0, 0);
    f32x4 p1 = __builtin_amdgcn_mfma_f32_16x16x32_f16(wp[1], mk8(od[0]), bp[1], 0, 0, 0);

    // final: out channels {4q..4q+3} and {16+4q..16+4q+3} of batch b (f32 exact)
    half2_t y0 = u2h(yd[0][0]), y1 = u2h(yd[0][1]), y2 = u2h(yd[0][2]), y3 = u2h(yd[0][3]);
    float f[8] = {(float)y0.x + p0[0], (float)y0.y + p0[1],
                  (float)y1.x + p0[2], (float)y1.y + p0[3],
                  (float)y2.x + p1[0], (float)y2.y + p1[1],
                  (float)y3.x + p1[2], (float)y3.y + p1[3]};
    if (isbf) {
      unsigned short* op = (unsigned short*)out + b * 32;
      *(uint2*)(op + 4 * quad) = make_uint2(f2bfpair(f[0], f[1]), f2bfpair(f[2], f[3]));
      *(uint2*)(op + 16 + 4 * quad) = make_uint2(f2bfpair(f[4], f[5]), f2bfpair(f[6], f[7]));
    } else {
      float* op = (float*)out + b * 32;
      *(float4*)(op + 4 * quad) = make_float4(f[0], f[1], f[2], f[3]);
      *(float4*)(op + 16 + 4 * quad) = make_float4(f[4], f[5], f[6], f[7]);
    }
  }
}

extern "C" void kernel_launch(void* const* d_in, const int* in_sizes, int n_in,
                              void* d_out, int out_size, void* d_ws, size_t ws_size,
                              hipStream_t stream) {
  const void* x      = d_in[0];
  const void* token  = d_in[1];
  const void* qkv_w  = d_in[2];
  const void* qkv_b  = d_in[3];
  const void* proj_w = d_in[4];
  const void* proj_b = d_in[5];
  const void* pos_b  = d_in[6];

  char* ws = (char*)d_ws;
  unsigned int* wqkv  = (unsigned int*)(ws + 0);
  unsigned int* wproj = (unsigned int*)(ws + 12288);
  float* bqkv  = (float*)(ws + 16384);
  float* bproj = (float*)(ws + 17152);
  float* pb    = (float*)(ws + 17408);
  int*   flag  = (int*)(ws + 19008);

  prep_kernel<<<8, 256, 0, stream>>>(x, qkv_w, qkv_b, proj_w, proj_b, pos_b,
                                     wqkv, wproj, bqkv, bproj, pb, flag);

  const int nrows = in_sizes[0] / 128;  // 262144 batch rows
  const int grid = nrows / 64;          // 64 rows per 256-thread block (4 waves x 16)
  vit_kernel<<<grid, 256, 0, stream>>>(x, token, wqkv, wproj, bqkv, bproj, pb, flag, d_out);
}